// Round 8
// baseline (327.069 us; speedup 1.0000x reference)
//
#include <hip/hip_runtime.h>
#include <float.h>

#define N_PART 262144
#define GRID_DIM 256
#define NUM_CELLS (GRID_DIM * GRID_DIM)
#define KP 32                          // padded slots per cell (= reference K)
#define MAXNB 64

// ---------------- ws layout (all 256B-aligned) ----------------
// counts : NUM_CELLS+1 ints   (zeroed in D1; [NUM_CELLS] stays 0 = clip row)
// bMinX/Y/H : 1024 floats each (per-block reduce partials)
// lin    : N ints             (cell of each particle)
// tableA : (NUM_CELLS+1)*KP ints   (raw ids, arrival order)
// Qpad   : (NUM_CELLS+1)*KP + 64 float4  ({x, y, id-bits, S}, id-sorted)
//
// Dispatch economics (r3/r5): grid.sync costs ~ a dispatch boundary, so no
// cooperative fusion. FOUR ordinary full-occupancy dispatches.
// Query economics (r6/r7 vs r2): wave-per-cell amortization was a loss --
// the limiter is WAVE COUNT (latency hiding), not per-wave setup. r7 null
// result: software pipelining changed nothing (VALU 29%, occ 40%). This
// version: one wave per (cell,slot) = 524288 waves, cell-major locality.

__global__ __launch_bounds__(256) void prep_kernel(
        const float2* __restrict__ pos2, const float* __restrict__ sup,
        int* __restrict__ counts,
        float* __restrict__ bMinX, float* __restrict__ bMinY,
        float* __restrict__ bMaxH) {
    __shared__ unsigned s_minx, s_miny, s_maxh;
    int t = threadIdx.x, b = blockIdx.x;
    int tid = b * 256 + t;
    if (tid <= NUM_CELLS) counts[tid] = 0;
    if (t == 0) { s_minx = 0x7f7fffffu; s_miny = 0x7f7fffffu; s_maxh = 0u; }
    __syncthreads();
    float2 p = pos2[tid];
    float  h = sup[tid];
    // non-negative floats: uint compare == float compare
    atomicMin(&s_minx, __float_as_uint(p.x));
    atomicMin(&s_miny, __float_as_uint(p.y));
    atomicMax(&s_maxh, __float_as_uint(h));
    __syncthreads();
    if (t == 0) {
        bMinX[b] = __uint_as_float(s_minx);
        bMinY[b] = __uint_as_float(s_miny);
        bMaxH[b] = __uint_as_float(s_maxh);
    }
}

__global__ __launch_bounds__(256) void bin_kernel(
        const float2* __restrict__ pos2,
        const float* __restrict__ bMinX, const float* __restrict__ bMinY,
        const float* __restrict__ bMaxH,
        int* __restrict__ counts, int* __restrict__ tableA,
        int* __restrict__ lin) {
    __shared__ unsigned s_minx, s_miny, s_maxh;
    int t = threadIdx.x;
    int tid = blockIdx.x * 256 + t;
    // redundant per-block combine of 1024 partials: min/max exact and
    // order-independent -> identical result in every block
    if (t == 0) { s_minx = 0x7f7fffffu; s_miny = 0x7f7fffffu; s_maxh = 0u; }
    __syncthreads();
    {
        float mx = FLT_MAX, my = FLT_MAX, mh = 0.0f;
        for (int k = t; k < 1024; k += 256) {
            mx = fminf(mx, bMinX[k]);
            my = fminf(my, bMinY[k]);
            mh = fmaxf(mh, bMaxH[k]);
        }
        atomicMin(&s_minx, __float_as_uint(mx));
        atomicMin(&s_miny, __float_as_uint(my));
        atomicMax(&s_maxh, __float_as_uint(mh));
    }
    __syncthreads();
    float hmax  = __uint_as_float(s_maxh);
    float qminx = __uint_as_float(s_minx) - hmax;
    float qminy = __uint_as_float(s_miny) - hmax;
    float2 p = pos2[tid];
    int cx = (int)ceilf((p.x - qminx) / hmax);
    int cy = (int)ceilf((p.y - qminy) / hmax);
    cx = min(max(cx, 0), GRID_DIM - 1);
    cy = min(max(cy, 0), GRID_DIM - 1);
    int c = cx + GRID_DIM * cy;
    lin[tid] = c;
    int slot = atomicAdd(&counts[c], 1);
    if (slot < KP) tableA[(c << 5) + slot] = tid;   // Poisson(4): never >32
}

// per particle: rank = #(smaller ids in my cell row) -> write the packed
// record at its FINAL id-sorted position (stable argsort semantics).
// Also precompute S = exact f32 threshold:  s2 <= S  <=>  RN(sqrt(s2)) <= h
// mid = (h + nextafterf(h))/2; mid^2 exact in double (50 bits), never a
// 24-bit f32 -> no ties; S = largest f32 <= mid^2.
__global__ __launch_bounds__(256) void rank_kernel(
        const float2* __restrict__ pos2, const float* __restrict__ sup,
        const int* __restrict__ counts, const int* __restrict__ tableA,
        const int* __restrict__ lin, float4* __restrict__ Qpad) {
    int tid = blockIdx.x * 256 + threadIdx.x;
    int c   = lin[tid];
    int cnt = min(counts[c], KP);
    const int* row = tableA + (c << 5);
    int rank = 0;
    for (int k = 0; k < cnt; k++) rank += (row[k] < tid);
    float2 p = pos2[tid];               // bitwise copy: query numerics identical
    float  h = sup[tid];
    float  hn  = __int_as_float(__float_as_int(h) + 1);     // nextafter(h,inf)
    double mid = 0.5 * ((double)h + (double)hn);
    double t2  = mid * mid;                                  // exact
    float  S   = (float)t2;                                  // RN
    S = ((double)S > t2) ? __int_as_float(__float_as_int(S) - 1) : S;
    Qpad[(c << 5) + rank] = make_float4(p.x, p.y, __int_as_float(tid), S);
}

// One wave per (CELL, SLOT): 524288 waves -- 2x round-2's parallelism with
// round-6's cell-major locality. Wave (c,s) handles sorted slot s of cell c
// (s==7 wave mops up slots 7..cnt-1, P~5%); waves with s>=cnt exit after a
// single load (~half, cheap). Per-wave body = the r6 verified single-
// particle path: 9-cell cum/delta from counts (L1-hot: 8 sibling waves +
// neighbor cells share lines), register-cached 64-lane candidate window,
// own record via readlane (zero loads, S precomputed in rank_kernel),
// masked-ballot stable compaction, LDS bounce, full 256B row stores.
__global__ __launch_bounds__(256) void query_kernel(
        const int* __restrict__ counts, const float4* __restrict__ Qpad,
        float* __restrict__ outN, float* __restrict__ outC,
        float* __restrict__ outR) {
#pragma clang fp contract(off)
    __shared__ int   s_id[4][MAXNB];
    __shared__ float s_s2[4][MAXNB];

    int t    = threadIdx.x;
    int lane = t & 63;
    int wsl  = t >> 6;
    int bid  = blockIdx.x;
    int swz  = (bid & 7) * (int)(gridDim.x >> 3) + (bid >> 3);  // bijective XCD
    int W    = __builtin_amdgcn_readfirstlane(swz * 4 + wsl);   // global wave
    int cell = W >> 3;
    int slot = W & 7;

    int cnt = min(__builtin_amdgcn_readfirstlane(counts[cell]), KP);
    if (slot >= cnt) return;            // no LDS/barrier deps: safe early-out
    int slast = (slot == 7) ? cnt : (slot + 1);

    const int offs[9] = {-257, -1, 255, -256, 0, 256, -255, 1, 257};
    int cum[10], delta[9];
    cum[0] = 0;
#pragma unroll
    for (int o = 0; o < 9; o++) {
        int cl = min(max(cell + offs[o], 0), NUM_CELLS);  // clip, dups at edges
        int cc = (o == 4) ? cnt
                          : min(__builtin_amdgcn_readfirstlane(counts[cl]), KP);
        delta[o]   = (cl << 5) - cum[o];                  // idx = ll + delta[o]
        cum[o + 1] = cum[o] + cc;
    }
    int T = cum[9];

    if (T <= 64) {
        // ---- fast path: one candidate per lane, cached in registers ----
        int dsel = delta[0];
#pragma unroll
        for (int m = 1; m < 9; m++)
            dsel = (lane >= cum[m]) ? delta[m] : dsel;
        float4 q = Qpad[lane + dsel];   // lanes >= T read in-bounds garbage
                                        //  (Qpad +64 pad); masked by maskT
        unsigned long long maskT = (T >= 64) ? ~0ull : ((1ull << T) - 1ull);
        for (int sl = slot; sl < slast; sl++) {
            int src = cum[4] + sl;      // lane holding my particle's record
            float px = __int_as_float(__builtin_amdgcn_readlane(__float_as_int(q.x), src));
            float py = __int_as_float(__builtin_amdgcn_readlane(__float_as_int(q.y), src));
            int   ib = __builtin_amdgcn_readlane(__float_as_int(q.z), src);
            float S  = __int_as_float(__builtin_amdgcn_readlane(__float_as_int(q.w), src));
            float dx = q.x - px;
            float dy = q.y - py;
            float s2 = dx * dx + dy * dy;          // contract(off): match XLA
            bool keep = (s2 <= S) && (lane < T);   // garbage lanes masked
            unsigned long long bal = __ballot(s2 <= S) & maskT;
            int rank = __builtin_amdgcn_mbcnt_hi(
                (unsigned)(bal >> 32),
                __builtin_amdgcn_mbcnt_lo((unsigned)bal, 0));
            if (keep) {                            // T<=64 -> rank < 64 always
                s_id[wsl][rank] = __float_as_int(q.z);
                s_s2[wsl][rank] = s2;
            }
            int total = (int)__popcll(bal);
            // wave-private LDS, same-wave DS ops ordered: no barrier. Stale
            // entries beyond 'total' discarded by the inb select.
            int   jj = s_id[wsl][lane];
            float ss = s_s2[wsl][lane];
            bool inb = lane < total;
            float rh = __builtin_amdgcn_rsqf(S);   // ~1/h, 1ulp; tol-covered
            float vN = inb ? (float)jj : -1.0f;
            float vR = inb ? __builtin_amdgcn_sqrtf(ss) * rh : 0.0f;
            size_t base = (size_t)ib * MAXNB;      // 256B row, fully written
            outN[base + lane] = vN;
            outR[base + lane] = vR;
            if (lane == 0) outC[ib] = (float)total;
        }
    } else {
        // ---- rare path (P(T>64) ~ 1e-5 per cell): batched, re-loads ----
        for (int sl = slot; sl < slast; sl++) {
            float4 me = Qpad[(cell << 5) + sl];
            int   ib = __builtin_amdgcn_readfirstlane(__float_as_int(me.z));
            float px = __int_as_float(__builtin_amdgcn_readfirstlane(__float_as_int(me.x)));
            float py = __int_as_float(__builtin_amdgcn_readfirstlane(__float_as_int(me.y)));
            float S  = __int_as_float(__builtin_amdgcn_readfirstlane(__float_as_int(me.w)));
            int total = 0;
            for (int b0 = 0; b0 < T; b0 += 64) {
                int ll = b0 + lane;
                int dsel = delta[0];
#pragma unroll
                for (int m = 1; m < 9; m++)
                    dsel = (ll >= cum[m]) ? delta[m] : dsel;
                float4 q = Qpad[ll + dsel];
                float dx = q.x - px;
                float dy = q.y - py;
                float s2 = dx * dx + dy * dy;
                int rem = T - b0;
                unsigned long long maskT =
                    (rem >= 64) ? ~0ull : ((1ull << rem) - 1ull);
                unsigned long long bal = __ballot(s2 <= S) & maskT;
                int rank = __builtin_amdgcn_mbcnt_hi(
                    (unsigned)(bal >> 32),
                    __builtin_amdgcn_mbcnt_lo((unsigned)bal, 0));
                int w = total + rank;
                if ((s2 <= S) && (ll < T) && (w < MAXNB)) {
                    s_id[wsl][w] = __float_as_int(q.z);
                    s_s2[wsl][w] = s2;
                }
                total += (int)__popcll(bal);
            }
            int stored = min(total, MAXNB);
            int   jj = s_id[wsl][lane];
            float ss = s_s2[wsl][lane];
            bool inb = lane < stored;
            float rh = __builtin_amdgcn_rsqf(S);
            float vN = inb ? (float)jj : -1.0f;
            float vR = inb ? __builtin_amdgcn_sqrtf(ss) * rh : 0.0f;
            size_t base = (size_t)ib * MAXNB;
            outN[base + lane] = vN;
            outR[base + lane] = vR;
            if (lane == 0) outC[ib] = (float)total;
        }
    }
}

extern "C" void kernel_launch(void* const* d_in, const int* in_sizes, int n_in,
                              void* d_out, int out_size, void* d_ws, size_t ws_size,
                              hipStream_t stream) {
    const float2* pos2 = (const float2*)d_in[0];
    const float*  sup  = (const float*)d_in[1];

    char* p = (char*)d_ws;
    auto alloc = [&](size_t bytes) {
        char* q = p;
        p += (bytes + 255) & ~(size_t)255;
        return q;
    };
    int*    counts = (int*)alloc((size_t)(NUM_CELLS + 1) * 4);
    float*  bMinX  = (float*)alloc(1024 * 4);
    float*  bMinY  = (float*)alloc(1024 * 4);
    float*  bMaxH  = (float*)alloc(1024 * 4);
    int*    lin    = (int*)alloc((size_t)N_PART * 4);
    int*    tableA = (int*)alloc((size_t)(NUM_CELLS + 1) * KP * 4);
    float4* Qpad   = (float4*)alloc(((size_t)(NUM_CELLS + 1) * KP + 64) * 16);

    float* out  = (float*)d_out;
    float* outN = out;                              // N*64 neighbor ids (as f32)
    float* outC = out + (size_t)N_PART * MAXNB;     // N counts
    float* outR = outC + N_PART;                    // N*64 radial

    prep_kernel<<<N_PART / 256, 256, 0, stream>>>(pos2, sup, counts,
                                                  bMinX, bMinY, bMaxH);
    bin_kernel<<<N_PART / 256, 256, 0, stream>>>(pos2, bMinX, bMinY, bMaxH,
                                                 counts, tableA, lin);
    rank_kernel<<<N_PART / 256, 256, 0, stream>>>(pos2, sup, counts, tableA,
                                                  lin, Qpad);
    // one wave per (cell, slot): NUM_CELLS*8 waves = NUM_CELLS*2 blocks
    query_kernel<<<NUM_CELLS * 2, 256, 0, stream>>>(counts, Qpad,
                                                    outN, outC, outR);
}

// Round 9
// 270.603 us; speedup vs baseline: 1.2087x; 1.2087x over previous
//
#include <hip/hip_runtime.h>
#include <float.h>

#define N_PART 262144
#define GRID_DIM 256
#define NUM_CELLS (GRID_DIM * GRID_DIM)
#define KP 32                          // padded slots per cell (= reference K)
#define MAXNB 64

// ---------------- ws layout (all 256B-aligned) ----------------
// counts : NUM_CELLS+1 ints   (zeroed in D1; [NUM_CELLS] stays 0 = clip row)
// bMinX/Y/H : 1024 floats each (per-block reduce partials)
// tableA : (NUM_CELLS+1)*KP ints   (raw ids, arrival order)
// Qpad   : (NUM_CELLS+1)*KP + 64 float4  ({x, y, id-bits, S}, id-sorted)
//
// Dispatch economics (r3/r5): grid.sync costs ~ a dispatch boundary, so no
// cooperative fusion. FOUR ordinary full-occupancy dispatches.
// Query economics (r2/r6/r7/r8): wave-per-cell register-window = 109us is
// the best compatible with this build; per-(cell,slot) waves regressed
// (readlane serializes own-record behind the window gather + 50% duds).
// This round: build-side only. rank was tid-ordered (random 128B row
// gathers + random 16B Qpad writes -> RMW thrash); now (cell,slot)-
// parallel: coalesced row reads, adjacent-row writes, lin[] eliminated.

__global__ __launch_bounds__(256) void prep_kernel(
        const float2* __restrict__ pos2, const float* __restrict__ sup,
        int* __restrict__ counts,
        float* __restrict__ bMinX, float* __restrict__ bMinY,
        float* __restrict__ bMaxH) {
    __shared__ unsigned s_minx, s_miny, s_maxh;
    int t = threadIdx.x, b = blockIdx.x;
    int tid = b * 256 + t;
    if (tid <= NUM_CELLS) counts[tid] = 0;
    if (t == 0) { s_minx = 0x7f7fffffu; s_miny = 0x7f7fffffu; s_maxh = 0u; }
    __syncthreads();
    float2 p = pos2[tid];
    float  h = sup[tid];
    // non-negative floats: uint compare == float compare
    atomicMin(&s_minx, __float_as_uint(p.x));
    atomicMin(&s_miny, __float_as_uint(p.y));
    atomicMax(&s_maxh, __float_as_uint(h));
    __syncthreads();
    if (t == 0) {
        bMinX[b] = __uint_as_float(s_minx);
        bMinY[b] = __uint_as_float(s_miny);
        bMaxH[b] = __uint_as_float(s_maxh);
    }
}

__global__ __launch_bounds__(256) void bin_kernel(
        const float2* __restrict__ pos2,
        const float* __restrict__ bMinX, const float* __restrict__ bMinY,
        const float* __restrict__ bMaxH,
        int* __restrict__ counts, int* __restrict__ tableA) {
    __shared__ unsigned s_minx, s_miny, s_maxh;
    int t = threadIdx.x;
    int tid = blockIdx.x * 256 + t;
    // redundant per-block combine of 1024 partials: min/max exact and
    // order-independent -> identical result in every block
    if (t == 0) { s_minx = 0x7f7fffffu; s_miny = 0x7f7fffffu; s_maxh = 0u; }
    __syncthreads();
    {
        float mx = FLT_MAX, my = FLT_MAX, mh = 0.0f;
        for (int k = t; k < 1024; k += 256) {
            mx = fminf(mx, bMinX[k]);
            my = fminf(my, bMinY[k]);
            mh = fmaxf(mh, bMaxH[k]);
        }
        atomicMin(&s_minx, __float_as_uint(mx));
        atomicMin(&s_miny, __float_as_uint(my));
        atomicMax(&s_maxh, __float_as_uint(mh));
    }
    __syncthreads();
    float hmax  = __uint_as_float(s_maxh);
    float qminx = __uint_as_float(s_minx) - hmax;
    float qminy = __uint_as_float(s_miny) - hmax;
    float2 p = pos2[tid];
    int cx = (int)ceilf((p.x - qminx) / hmax);
    int cy = (int)ceilf((p.y - qminy) / hmax);
    cx = min(max(cx, 0), GRID_DIM - 1);
    cy = min(max(cy, 0), GRID_DIM - 1);
    int c = cx + GRID_DIM * cy;
    int slot = atomicAdd(&counts[c], 1);
    if (slot < KP) tableA[(c << 5) + slot] = tid;   // Poisson(4): never >32
}

// (cell,slot)-parallel ordered emit: thread (c,s), s in [0,8), handles
// arrival slots s, s+8, ... of cell c (one iter for ~all cells). 16
// consecutive threads read 2 consecutive tableA rows -> coalesced; Qpad
// writes land in adjacent rows -> coalesced at L2. rank = #(smaller ids in
// row) puts the record at its id-sorted position (stable argsort
// semantics). Also precompute S = exact f32 threshold:
//   s2 <= S  <=>  RN(sqrt(s2)) <= h
// mid = (h + nextafterf(h))/2; mid^2 exact in double (50 bits), never a
// 24-bit f32 -> no ties; S = largest f32 <= mid^2.
__global__ __launch_bounds__(256) void rank_kernel(
        const float2* __restrict__ pos2, const float* __restrict__ sup,
        const int* __restrict__ counts, const int* __restrict__ tableA,
        float4* __restrict__ Qpad) {
    int tid = blockIdx.x * 256 + threadIdx.x;   // NUM_CELLS*8 threads
    int c   = tid >> 3;
    int s0  = tid & 7;
    int cnt = min(counts[c], KP);
    const int* row = tableA + (c << 5);
    for (int sl = s0; sl < cnt; sl += 8) {
        int id = row[sl];
        int rank = 0;
        for (int k = 0; k < cnt; k++) rank += (row[k] < id);
        float2 p = pos2[id];            // bitwise copy: query numerics identical
        float  h = sup[id];
        float  hn  = __int_as_float(__float_as_int(h) + 1); // nextafter(h,inf)
        double mid = 0.5 * ((double)h + (double)hn);
        double t2  = mid * mid;                              // exact
        float  S   = (float)t2;                              // RN
        S = ((double)S > t2) ? __int_as_float(__float_as_int(S) - 1) : S;
        Qpad[(c << 5) + rank] = make_float4(p.x, p.y, __int_as_float(id), S);
    }
}

// One wave per CELL (r6-verified, byte-identical): 9-cell cum/delta from
// counts (L1-hot), register-cached 64-lane candidate window, own record via
// readlane, masked-ballot stable compaction, LDS bounce, full 256B row
// stores. The reference's RN(sqrt(s2)) <= h collapses to one v_cmp_le_f32
// against the precomputed S; sqrt only per stored lane (v_sqrt*v_rcp,
// ~3ulp, inside comparator tolerance -- absmax 0.0039 passed r6/r7).
__global__ __launch_bounds__(256) void query_kernel(
        const int* __restrict__ counts, const float4* __restrict__ Qpad,
        float* __restrict__ outN, float* __restrict__ outC,
        float* __restrict__ outR) {
#pragma clang fp contract(off)
    __shared__ int   s_id[4][MAXNB];
    __shared__ float s_s2[4][MAXNB];

    int t    = threadIdx.x;
    int lane = t & 63;
    int wsl  = t >> 6;
    int bid  = blockIdx.x;
    int swz  = (bid & 7) * (int)(gridDim.x >> 3) + (bid >> 3);  // bijective XCD
    int cell = __builtin_amdgcn_readfirstlane(swz * 4 + wsl);

    const int offs[9] = {-257, -1, 255, -256, 0, 256, -255, 1, 257};
    int cum[10], delta[9];
    cum[0] = 0;
#pragma unroll
    for (int o = 0; o < 9; o++) {
        int cl = min(max(cell + offs[o], 0), NUM_CELLS);  // clip, dups at edges
        int cc = min(__builtin_amdgcn_readfirstlane(counts[cl]), KP);
        delta[o]   = (cl << 5) - cum[o];                  // idx = ll + delta[o]
        cum[o + 1] = cum[o] + cc;
    }
    int T   = cum[9];
    int cnt = cum[5] - cum[4];          // center-cell count (= my particles)
    if (cnt == 0) return;               // no LDS/barrier deps: safe early-out

    if (T <= 64) {
        // ---- fast path: one candidate per lane, cached in registers ----
        int dsel = delta[0];
#pragma unroll
        for (int m = 1; m < 9; m++)
            dsel = (lane >= cum[m]) ? delta[m] : dsel;
        float4 q = Qpad[lane + dsel];   // lanes >= T read in-bounds garbage
                                        //  (Qpad +64 pad); masked by maskT
        unsigned long long maskT = (T >= 64) ? ~0ull : ((1ull << T) - 1ull);
        for (int s = 0; s < cnt; s++) {
            int src = cum[4] + s;       // lane holding my particle's record
            float px = __int_as_float(__builtin_amdgcn_readlane(__float_as_int(q.x), src));
            float py = __int_as_float(__builtin_amdgcn_readlane(__float_as_int(q.y), src));
            int   ib = __builtin_amdgcn_readlane(__float_as_int(q.z), src);
            float S  = __int_as_float(__builtin_amdgcn_readlane(__float_as_int(q.w), src));
            float dx = q.x - px;
            float dy = q.y - py;
            float s2 = dx * dx + dy * dy;          // contract(off): match XLA
            bool keep = (s2 <= S) && (lane < T);   // garbage lanes masked
            unsigned long long bal = __ballot(s2 <= S) & maskT;
            int rank = __builtin_amdgcn_mbcnt_hi(
                (unsigned)(bal >> 32),
                __builtin_amdgcn_mbcnt_lo((unsigned)bal, 0));
            if (keep) {                            // T<=64 -> rank < 64 always
                s_id[wsl][rank] = __float_as_int(q.z);
                s_s2[wsl][rank] = s2;
            }
            int total = (int)__popcll(bal);
            // wave-private LDS, same-wave DS ops ordered: no barrier. Stale
            // entries beyond 'total' discarded by the inb select.
            int   jj = s_id[wsl][lane];
            float ss = s_s2[wsl][lane];
            bool inb = lane < total;
            float rh = __builtin_amdgcn_rsqf(S);   // ~1/h, 1ulp; tol-covered
            float vN = inb ? (float)jj : -1.0f;
            float vR = inb ? __builtin_amdgcn_sqrtf(ss) * rh : 0.0f;
            size_t base = (size_t)ib * MAXNB;      // 256B row, fully written
            outN[base + lane] = vN;
            outR[base + lane] = vR;
            if (lane == 0) outC[ib] = (float)total;
        }
    } else {
        // ---- rare path (P(T>64) ~ 1e-5 per cell): batched, re-loads ----
        for (int s = 0; s < cnt; s++) {
            float4 me = Qpad[(cell << 5) + s];
            int   ib = __builtin_amdgcn_readfirstlane(__float_as_int(me.z));
            float px = __int_as_float(__builtin_amdgcn_readfirstlane(__float_as_int(me.x)));
            float py = __int_as_float(__builtin_amdgcn_readfirstlane(__float_as_int(me.y)));
            float S  = __int_as_float(__builtin_amdgcn_readfirstlane(__float_as_int(me.w)));
            int total = 0;
            for (int b0 = 0; b0 < T; b0 += 64) {
                int ll = b0 + lane;
                int dsel = delta[0];
#pragma unroll
                for (int m = 1; m < 9; m++)
                    dsel = (ll >= cum[m]) ? delta[m] : dsel;
                float4 q = Qpad[ll + dsel];
                float dx = q.x - px;
                float dy = q.y - py;
                float s2 = dx * dx + dy * dy;
                int rem = T - b0;
                unsigned long long maskT =
                    (rem >= 64) ? ~0ull : ((1ull << rem) - 1ull);
                unsigned long long bal = __ballot(s2 <= S) & maskT;
                int rank = __builtin_amdgcn_mbcnt_hi(
                    (unsigned)(bal >> 32),
                    __builtin_amdgcn_mbcnt_lo((unsigned)bal, 0));
                int w = total + rank;
                if ((s2 <= S) && (ll < T) && (w < MAXNB)) {
                    s_id[wsl][w] = __float_as_int(q.z);
                    s_s2[wsl][w] = s2;
                }
                total += (int)__popcll(bal);
            }
            int stored = min(total, MAXNB);
            int   jj = s_id[wsl][lane];
            float ss = s_s2[wsl][lane];
            bool inb = lane < stored;
            float rh = __builtin_amdgcn_rsqf(S);
            float vN = inb ? (float)jj : -1.0f;
            float vR = inb ? __builtin_amdgcn_sqrtf(ss) * rh : 0.0f;
            size_t base = (size_t)ib * MAXNB;
            outN[base + lane] = vN;
            outR[base + lane] = vR;
            if (lane == 0) outC[ib] = (float)total;
        }
    }
}

extern "C" void kernel_launch(void* const* d_in, const int* in_sizes, int n_in,
                              void* d_out, int out_size, void* d_ws, size_t ws_size,
                              hipStream_t stream) {
    const float2* pos2 = (const float2*)d_in[0];
    const float*  sup  = (const float*)d_in[1];

    char* p = (char*)d_ws;
    auto alloc = [&](size_t bytes) {
        char* q = p;
        p += (bytes + 255) & ~(size_t)255;
        return q;
    };
    int*    counts = (int*)alloc((size_t)(NUM_CELLS + 1) * 4);
    float*  bMinX  = (float*)alloc(1024 * 4);
    float*  bMinY  = (float*)alloc(1024 * 4);
    float*  bMaxH  = (float*)alloc(1024 * 4);
    int*    tableA = (int*)alloc((size_t)(NUM_CELLS + 1) * KP * 4);
    float4* Qpad   = (float4*)alloc(((size_t)(NUM_CELLS + 1) * KP + 64) * 16);

    float* out  = (float*)d_out;
    float* outN = out;                              // N*64 neighbor ids (as f32)
    float* outC = out + (size_t)N_PART * MAXNB;     // N counts
    float* outR = outC + N_PART;                    // N*64 radial

    prep_kernel<<<N_PART / 256, 256, 0, stream>>>(pos2, sup, counts,
                                                  bMinX, bMinY, bMaxH);
    bin_kernel<<<N_PART / 256, 256, 0, stream>>>(pos2, bMinX, bMinY, bMaxH,
                                                 counts, tableA);
    // thread per (cell, slot-class): NUM_CELLS*8 threads
    rank_kernel<<<NUM_CELLS * 8 / 256, 256, 0, stream>>>(pos2, sup, counts,
                                                         tableA, Qpad);
    // one wave per cell: NUM_CELLS waves, 4 cells per 256-thread block
    query_kernel<<<NUM_CELLS / 4, 256, 0, stream>>>(counts, Qpad,
                                                    outN, outC, outR);
}

// Round 10
// 267.435 us; speedup vs baseline: 1.2230x; 1.0118x over previous
//
#include <hip/hip_runtime.h>
#include <float.h>

#define N_PART 262144
#define GRID_DIM 256
#define NUM_CELLS (GRID_DIM * GRID_DIM)
#define KP 32                          // padded slots per cell (= reference K)
#define MAXNB 64

// ---------------- ws layout (all 256B-aligned) ----------------
// counts : NUM_CELLS+1 ints   (zeroed in D1; [NUM_CELLS] stays 0 = clip row)
// bMinX/Y/H : 1024 floats each (per-block reduce partials)
// tableA : (NUM_CELLS+1)*KP ints   (raw ids, arrival order)
// Qpad   : (NUM_CELLS+1)*KP + 64 float4  ({x, y, id-bits, S}, id-sorted)
// linR   : N ints              ((cell<<5)|rank per particle id)
// cinfo  : NUM_CELLS*3 int4    (9-cell prefix sums cum[1..9] per cell)
//
// Dispatch economics (r3/r5): grid.sync costs ~ a dispatch boundary, so no
// cooperative fusion. FOUR ordinary full-occupancy dispatches.
// Query economics (r2..r9): all prior query shapes pinned at 89-164us with
// writes at only ~1.4 TB/s -- the output rows are id-addressed but waves ran
// cell-sorted, so the 140MB write stream was RANDOM 256B bursts (DRAM page
// thrash). This round: waves in ID order (sequential writes); rank_kernel
// pre-computes linR + per-cell prefix sums so the id-ordered wave's setup is
// 5 uniform loads, no readlane-after-gather serialization (r8's mistake).

__global__ __launch_bounds__(256) void prep_kernel(
        const float2* __restrict__ pos2, const float* __restrict__ sup,
        int* __restrict__ counts,
        float* __restrict__ bMinX, float* __restrict__ bMinY,
        float* __restrict__ bMaxH) {
    __shared__ unsigned s_minx, s_miny, s_maxh;
    int t = threadIdx.x, b = blockIdx.x;
    int tid = b * 256 + t;
    if (tid <= NUM_CELLS) counts[tid] = 0;
    if (t == 0) { s_minx = 0x7f7fffffu; s_miny = 0x7f7fffffu; s_maxh = 0u; }
    __syncthreads();
    float2 p = pos2[tid];
    float  h = sup[tid];
    // non-negative floats: uint compare == float compare
    atomicMin(&s_minx, __float_as_uint(p.x));
    atomicMin(&s_miny, __float_as_uint(p.y));
    atomicMax(&s_maxh, __float_as_uint(h));
    __syncthreads();
    if (t == 0) {
        bMinX[b] = __uint_as_float(s_minx);
        bMinY[b] = __uint_as_float(s_miny);
        bMaxH[b] = __uint_as_float(s_maxh);
    }
}

__global__ __launch_bounds__(256) void bin_kernel(
        const float2* __restrict__ pos2,
        const float* __restrict__ bMinX, const float* __restrict__ bMinY,
        const float* __restrict__ bMaxH,
        int* __restrict__ counts, int* __restrict__ tableA) {
    __shared__ unsigned s_minx, s_miny, s_maxh;
    int t = threadIdx.x;
    int tid = blockIdx.x * 256 + t;
    // redundant per-block combine of 1024 partials: min/max exact and
    // order-independent -> identical result in every block
    if (t == 0) { s_minx = 0x7f7fffffu; s_miny = 0x7f7fffffu; s_maxh = 0u; }
    __syncthreads();
    {
        float mx = FLT_MAX, my = FLT_MAX, mh = 0.0f;
        for (int k = t; k < 1024; k += 256) {
            mx = fminf(mx, bMinX[k]);
            my = fminf(my, bMinY[k]);
            mh = fmaxf(mh, bMaxH[k]);
        }
        atomicMin(&s_minx, __float_as_uint(mx));
        atomicMin(&s_miny, __float_as_uint(my));
        atomicMax(&s_maxh, __float_as_uint(mh));
    }
    __syncthreads();
    float hmax  = __uint_as_float(s_maxh);
    float qminx = __uint_as_float(s_minx) - hmax;
    float qminy = __uint_as_float(s_miny) - hmax;
    float2 p = pos2[tid];
    int cx = (int)ceilf((p.x - qminx) / hmax);
    int cy = (int)ceilf((p.y - qminy) / hmax);
    cx = min(max(cx, 0), GRID_DIM - 1);
    cy = min(max(cy, 0), GRID_DIM - 1);
    int c = cx + GRID_DIM * cy;
    int slot = atomicAdd(&counts[c], 1);
    if (slot < KP) tableA[(c << 5) + slot] = tid;   // Poisson(4): never >32
}

// (cell,slot)-parallel ordered emit (r9-verified) + two new side products:
//   linR[id]  = (c<<5)|rank           (id -> record address, coalesced-ish)
//   cinfo[c]  = cum[1..9]             (9-cell prefix sums, one thread/cell)
// rank = #(smaller ids in row) puts each record at its id-sorted position
// (stable argsort semantics). S = exact f32 threshold:
//   s2 <= S  <=>  RN(sqrt(s2)) <= h
// mid = (h + nextafterf(h))/2; mid^2 exact in double (50 bits), never a
// 24-bit f32 -> no ties; S = largest f32 <= mid^2.
__global__ __launch_bounds__(256) void rank_kernel(
        const float2* __restrict__ pos2, const float* __restrict__ sup,
        const int* __restrict__ counts, const int* __restrict__ tableA,
        float4* __restrict__ Qpad, int* __restrict__ linR,
        int4* __restrict__ cinfo) {
    int tid = blockIdx.x * 256 + threadIdx.x;   // NUM_CELLS*8 threads
    int c   = tid >> 3;
    int s0  = tid & 7;
    int cnt = min(counts[c], KP);
    const int* row = tableA + (c << 5);
    for (int sl = s0; sl < cnt; sl += 8) {
        int id = row[sl];
        int rank = 0;
        for (int k = 0; k < cnt; k++) rank += (row[k] < id);
        float2 p = pos2[id];            // bitwise copy: query numerics identical
        float  h = sup[id];
        float  hn  = __int_as_float(__float_as_int(h) + 1); // nextafter(h,inf)
        double mid = 0.5 * ((double)h + (double)hn);
        double t2  = mid * mid;                              // exact
        float  S   = (float)t2;                              // RN
        S = ((double)S > t2) ? __int_as_float(__float_as_int(S) - 1) : S;
        Qpad[(c << 5) + rank] = make_float4(p.x, p.y, __int_as_float(id), S);
        linR[id] = (c << 5) | rank;     // rank < 32: fits 5 bits
    }
    if (s0 == 0) {                      // one thread per cell: prefix sums
        const int offs[9] = {-257, -1, 255, -256, 0, 256, -255, 1, 257};
        int cum = 0;
        int v[9];
#pragma unroll
        for (int o = 0; o < 9; o++) {
            int cl = min(max(c + offs[o], 0), NUM_CELLS);   // clip, dups incl.
            cum += min(counts[cl], KP);
            v[o] = cum;
        }
        cinfo[c * 3 + 0] = make_int4(v[0], v[1], v[2], v[3]);
        cinfo[c * 3 + 1] = make_int4(v[4], v[5], v[6], v[7]);
        cinfo[c * 3 + 2] = make_int4(v[8], 0, 0, 0);
    }
}

// One wave per PARTICLE in ID ORDER: consecutive waves write consecutive
// 256B output rows -> sequential HBM write streams per XCD chunk (the prior
// cell-ordered versions wrote random 256B bursts at ~1.4 TB/s). Setup is 5
// uniform loads (linR, 3x cinfo, own record) -- no gather-dependent
// readlane (r8's serialization). Candidate gathers hit the ~7MB active
// Qpad/cinfo set in L2/LLC. Junk lanes (>=T) clamp to the own-record line.
// Candidate order, masked-ballot stable compaction, S-comparator, epilogue:
// byte-identical semantics to the r6-r9 verified path.
__global__ __launch_bounds__(256) void query_kernel(
        const int* __restrict__ linR, const int4* __restrict__ cinfo,
        const float4* __restrict__ Qpad,
        float* __restrict__ outN, float* __restrict__ outC,
        float* __restrict__ outR) {
#pragma clang fp contract(off)
    __shared__ int   s_id[4][MAXNB];
    __shared__ float s_s2[4][MAXNB];

    int t    = threadIdx.x;
    int lane = t & 63;
    int wsl  = t >> 6;
    int bid  = blockIdx.x;
    int swz  = (bid & 7) * (int)(gridDim.x >> 3) + (bid >> 3);  // bijective XCD
    int w    = __builtin_amdgcn_readfirstlane(swz * 4 + wsl);   // particle id

    int lr = __builtin_amdgcn_readfirstlane(linR[w]);
    int c  = lr >> 5;

    int4 ca = cinfo[c * 3 + 0];         // uniform broadcast loads
    int4 cb = cinfo[c * 3 + 1];
    int4 cz = cinfo[c * 3 + 2];
    float4 me = Qpad[lr];               // own record: {x, y, id-bits, S}
    float px = me.x, py = me.y, S = me.w;

    const int offs[9] = {-257, -1, 255, -256, 0, 256, -255, 1, 257};
    int cum[10] = {0, ca.x, ca.y, ca.z, ca.w, cb.x, cb.y, cb.z, cb.w, };
    cum[9] = cz.x;
    int T = cum[9];
    int delta[9];
#pragma unroll
    for (int o = 0; o < 9; o++) {
        int cl = min(max(c + offs[o], 0), NUM_CELLS);   // clip, dups at edges
        delta[o] = (cl << 5) - cum[o];                  // idx = ll + delta[o]
    }

    if (T <= 64) {
        // ---- fast path: one candidate per lane ----
        int dsel = delta[0];
#pragma unroll
        for (int m = 1; m < 9; m++)
            dsel = (lane >= cum[m]) ? delta[m] : dsel;
        int idx = (lane < T) ? (lane + dsel) : lr;      // clamp junk lanes to
        float4 q = Qpad[idx];                           //  the hot own-line
        unsigned long long maskT = (T >= 64) ? ~0ull : ((1ull << T) - 1ull);
        float dx = q.x - px;
        float dy = q.y - py;
        float s2 = dx * dx + dy * dy;          // contract(off): match XLA
        bool keep = (s2 <= S) && (lane < T);   // junk/own-clamp lanes masked
        unsigned long long bal = __ballot(s2 <= S) & maskT;
        int rank = __builtin_amdgcn_mbcnt_hi(
            (unsigned)(bal >> 32),
            __builtin_amdgcn_mbcnt_lo((unsigned)bal, 0));
        if (keep) {                            // T<=64 -> rank < 64 always
            s_id[wsl][rank] = __float_as_int(q.z);
            s_s2[wsl][rank] = s2;
        }
        int total = (int)__popcll(bal);
        // wave-private LDS, same-wave DS ops ordered: no barrier. Stale
        // entries beyond 'total' discarded by the inb select.
        int   jj = s_id[wsl][lane];
        float ss = s_s2[wsl][lane];
        bool inb = lane < total;
        float rh = __builtin_amdgcn_rsqf(S);   // ~1/h, 1ulp; tol-covered
        float vN = inb ? (float)jj : -1.0f;
        float vR = inb ? __builtin_amdgcn_sqrtf(ss) * rh : 0.0f;
        size_t base = (size_t)w * MAXNB;       // SEQUENTIAL across waves
        outN[base + lane] = vN;
        outR[base + lane] = vR;
        if (lane == 0) outC[w] = (float)total;
    } else {
        // ---- rare path (P(T>64) ~ 1e-5 per cell): batched, re-loads ----
        int total = 0;
        for (int b0 = 0; b0 < T; b0 += 64) {
            int ll = b0 + lane;
            int dsel = delta[0];
#pragma unroll
            for (int m = 1; m < 9; m++)
                dsel = (ll >= cum[m]) ? delta[m] : dsel;
            float4 q = Qpad[ll + dsel];        // <= pad: Qpad padded by 64
            float dx = q.x - px;
            float dy = q.y - py;
            float s2 = dx * dx + dy * dy;
            int rem = T - b0;
            unsigned long long maskT =
                (rem >= 64) ? ~0ull : ((1ull << rem) - 1ull);
            unsigned long long bal = __ballot(s2 <= S) & maskT;
            int rank = __builtin_amdgcn_mbcnt_hi(
                (unsigned)(bal >> 32),
                __builtin_amdgcn_mbcnt_lo((unsigned)bal, 0));
            int ww = total + rank;
            if ((s2 <= S) && (ll < T) && (ww < MAXNB)) {
                s_id[wsl][ww] = __float_as_int(q.z);
                s_s2[wsl][ww] = s2;
            }
            total += (int)__popcll(bal);
        }
        int stored = min(total, MAXNB);
        int   jj = s_id[wsl][lane];
        float ss = s_s2[wsl][lane];
        bool inb = lane < stored;
        float rh = __builtin_amdgcn_rsqf(S);
        float vN = inb ? (float)jj : -1.0f;
        float vR = inb ? __builtin_amdgcn_sqrtf(ss) * rh : 0.0f;
        size_t base = (size_t)w * MAXNB;
        outN[base + lane] = vN;
        outR[base + lane] = vR;
        if (lane == 0) outC[w] = (float)total;
    }
}

extern "C" void kernel_launch(void* const* d_in, const int* in_sizes, int n_in,
                              void* d_out, int out_size, void* d_ws, size_t ws_size,
                              hipStream_t stream) {
    const float2* pos2 = (const float2*)d_in[0];
    const float*  sup  = (const float*)d_in[1];

    char* p = (char*)d_ws;
    auto alloc = [&](size_t bytes) {
        char* q = p;
        p += (bytes + 255) & ~(size_t)255;
        return q;
    };
    int*    counts = (int*)alloc((size_t)(NUM_CELLS + 1) * 4);
    float*  bMinX  = (float*)alloc(1024 * 4);
    float*  bMinY  = (float*)alloc(1024 * 4);
    float*  bMaxH  = (float*)alloc(1024 * 4);
    int*    tableA = (int*)alloc((size_t)(NUM_CELLS + 1) * KP * 4);
    float4* Qpad   = (float4*)alloc(((size_t)(NUM_CELLS + 1) * KP + 64) * 16);
    int*    linR   = (int*)alloc((size_t)N_PART * 4);
    int4*   cinfo  = (int4*)alloc((size_t)NUM_CELLS * 3 * 16);

    float* out  = (float*)d_out;
    float* outN = out;                              // N*64 neighbor ids (as f32)
    float* outC = out + (size_t)N_PART * MAXNB;     // N counts
    float* outR = outC + N_PART;                    // N*64 radial

    prep_kernel<<<N_PART / 256, 256, 0, stream>>>(pos2, sup, counts,
                                                  bMinX, bMinY, bMaxH);
    bin_kernel<<<N_PART / 256, 256, 0, stream>>>(pos2, bMinX, bMinY, bMaxH,
                                                 counts, tableA);
    // thread per (cell, slot-class): NUM_CELLS*8 threads
    rank_kernel<<<NUM_CELLS * 8 / 256, 256, 0, stream>>>(pos2, sup, counts,
                                                         tableA, Qpad, linR,
                                                         cinfo);
    // one wave per particle, ID ORDER: N_PART waves = N_PART/4 blocks
    query_kernel<<<N_PART / 4, 256, 0, stream>>>(linR, cinfo, Qpad,
                                                 outN, outC, outR);
}